// Round 13
// baseline (172.552 us; speedup 1.0000x reference)
//
#include <hip/hip_runtime.h>
#include <math.h>

#define IN_C 512
#define HID  64
#define OUTC 40

typedef __attribute__((ext_vector_type(8))) short bf16x8;
typedef __attribute__((ext_vector_type(4))) float f32x4;

#define GDEPTH 16

__device__ __forceinline__ ushort f2bf(float f) {          // RNE
    uint u = __float_as_uint(f);
    u += 0x7FFFu + ((u >> 16) & 1u);
    return (ushort)(u >> 16);
}
__device__ __forceinline__ float bf2f(ushort s) {
    return __uint_as_float(((uint)s) << 16);
}

// async global->LDS, 16B per lane; lds base must be wave-uniform (HW adds lane*16)
__device__ __forceinline__ void gl_lds16(const void* g, void* l) {
    __builtin_amdgcn_global_load_lds(
        (const __attribute__((address_space(1))) void*)g,
        (__attribute__((address_space(3))) void*)l,
        16, 0, 0);
}

// ---------------- zero cnt ----------------
__global__ void k_zero(int4* __restrict__ p, int n4) {
    int i = blockIdx.x * blockDim.x + threadIdx.x;
    if (i < n4) p[i] = make_int4(0, 0, 0, 0);
}

// ---------------- histogram of dst + per-edge rank (+ W1 split, K-tiled + XOR-swizzled pack) ---
// B pack: tile t, col c, kk=k&31. Logical byte in tile = c*64 + kk*2;
// physical = logical ^ (((logical>>6)&7)<<4)
__global__ void k_histsplit(const int* __restrict__ dst, int E,
                            int* __restrict__ cnt, int* __restrict__ rank,
                            int nbE2,
                            const float* __restrict__ W,
                            ushort* __restrict__ hi, ushort* __restrict__ lo) {
    if (blockIdx.x < (unsigned)nbE2) {
        int i = (blockIdx.x * blockDim.x + threadIdx.x) * 2;
        if (i < E) {
            if (i + 1 < E) {
                int2 d = *(const int2*)&dst[i];
                int r0 = atomicAdd(&cnt[d.x], 1);
                int r1 = atomicAdd(&cnt[d.y], 1);
                *(int2*)&rank[i] = make_int2(r0, r1);
            } else {
                rank[i] = atomicAdd(&cnt[dst[i]], 1);
            }
        }
    } else {
        int i = (blockIdx.x - nbE2) * blockDim.x + threadIdx.x;   // over 64*512
        if (i >= HID * IN_C) return;
        int c = i >> 9, k = i & 511;
        float v = W[(size_t)k * HID + c];
        uint ub = __float_as_uint(v);
        uint hb = ub & 0xFFFF0000u;
        float lf = v - __uint_as_float(hb);
        int lb = c * 64 + (k & 31) * 2;                   // logical byte in tile
        int pb = lb ^ (((lb >> 6) & 7) << 4);             // swizzled byte
        int pidx = (k >> 5) * 2048 + (pb >> 1);           // ushort index
        hi[pidx] = (ushort)(ub >> 16);
        lo[pidx] = (ushort)(__float_as_uint(lf) >> 16);
    }
}

// ---------------- prefix scan ----------------
__global__ void k_scan1(const int* __restrict__ cnt, int N,
                        int* __restrict__ rowptr, int* __restrict__ bsum) {
    __shared__ int s[256];
    int t = threadIdx.x;
    int i = blockIdx.x * 256 + t;
    int v = (i < N) ? cnt[i] : 0;
    int x = v;
    s[t] = x; __syncthreads();
    #pragma unroll
    for (int o = 1; o < 256; o <<= 1) {
        int y = (t >= o) ? s[t - o] : 0;
        __syncthreads();
        x += y; s[t] = x;
        __syncthreads();
    }
    if (i < N) rowptr[i] = x - v;          // exclusive
    if (t == 255) bsum[blockIdx.x] = x;    // block total
}

// scan2+scan3 fused
__global__ void k_scan23(int* __restrict__ rowptr, const int* __restrict__ bsum,
                         const int* __restrict__ cnt, float* __restrict__ dinv,
                         int N, int E, int nb) {
    __shared__ int s[256];
    int t = threadIdx.x;
    int v = (t < nb) ? bsum[t] : 0;
    int x = v;
    s[t] = x; __syncthreads();
    #pragma unroll
    for (int o = 1; o < 256; o <<= 1) {
        int y = (t >= o) ? s[t - o] : 0;
        __syncthreads();
        x += y; s[t] = x;
        __syncthreads();
    }
    int bpre = (blockIdx.x > 0) ? s[blockIdx.x - 1] : 0;
    int i = blockIdx.x * 256 + t;
    if (i < N) {
        rowptr[i] += bpre;
        dinv[i] = rsqrtf(1.0f + (float)cnt[i]);   // self-loop => deg >= 1
        if (i == 0) rowptr[N] = E;
    }
}

// ---------------- counting-sort scatter (atomic-free, standalone) ----------------
__global__ void k_fill(const int* __restrict__ src, const int* __restrict__ dst,
                       const int* __restrict__ rank, int E,
                       const int* __restrict__ rowptr, int* __restrict__ ssort) {
    int i = (blockIdx.x * blockDim.x + threadIdx.x) * 2;
    if (i >= E) return;
    if (i + 1 < E) {
        int2 d = *(const int2*)&dst[i];
        int2 s = *(const int2*)&src[i];
        int2 r = *(const int2*)&rank[i];
        ssort[rowptr[d.x] + r.x] = s.x;
        ssort[rowptr[d.y] + r.y] = s.y;
    } else {
        ssort[rowptr[dst[i]] + rank[i]] = src[i];
    }
}

// ---------------- GEMM1: full-K A-resident tile, contiguous 64KB x-stream ----------------
// BM=32 rows/block. A: the block's ENTIRE x tile (32 contiguous rows = 64KB
// contiguous in HBM) staged once via global_load_lds (swizzled source, linear
// dest). B: K-tiled pre-swizzled bf16 hi/lo pack, double-buffered 4KB tiles
// from L2. f32->bf16 hi/lo split at fragment-read time. 80KB LDS -> 2 blk/CU.
__global__ __launch_bounds__(256) void k_gemm1(
        const float* __restrict__ x,
        const ushort* __restrict__ Bphi, const ushort* __restrict__ Bplo,
        const float* __restrict__ dinv, ushort* __restrict__ h1s, int N) {
    __shared__ float  Af[32 * 512];               // 64KB, row-XOR-swizzled
    __shared__ ushort Bh[2][2048], Bl[2][2048];   // 2 x (4KB + 4KB)

    int t = threadIdx.x;
    int wid = t >> 6, lane = t & 63;
    int lr = lane & 15, lko = lane >> 4;
    int wm = wid >> 1, wn = wid & 1;
    int row0 = blockIdx.x * 32;

    // ---- stage A: 16 issues/thread, source contiguous per row (swizzled chunks) ----
    const char* xb = (const char*)x;
    #pragma unroll
    for (int j = 0; j < 16; ++j) {
        int p = t * 16 + j * 4096;                // physical LDS byte
        int row = p >> 11;
        int o = (p & 2047) ^ ((row & 7) << 4);    // swizzled within-row byte
        int grow = row0 + row; if (grow >= N) grow = N - 1;
        gl_lds16(xb + (size_t)grow * 2048 + o, (char*)Af + j * 4096 + wid * 1024);
    }
    // ---- stage B tile 0 (linear: pack is pre-swizzled) ----
    const char* bsrcH = (const char*)Bphi + (size_t)t * 16;
    const char* bsrcL = (const char*)Bplo + (size_t)t * 16;
    gl_lds16(bsrcH, (char*)&Bh[0][0] + wid * 1024);
    gl_lds16(bsrcL, (char*)&Bl[0][0] + wid * 1024);
    __syncthreads();

    f32x4 acc[2] = {};

    #pragma unroll
    for (int i = 0; i < 16; ++i) {
        if (i < 15) {
            gl_lds16(bsrcH + (size_t)(i + 1) * 4096, (char*)&Bh[(i + 1) & 1][0] + wid * 1024);
            gl_lds16(bsrcL + (size_t)(i + 1) * 4096, (char*)&Bl[(i + 1) & 1][0] + wid * 1024);
        }
        // A fragment: row = wm*16+lr, k = i*32 + lko*8 (8 f32 -> hi/lo bf16)
        int row = wm * 16 + lr;
        int fi = (row * 512 + i * 32 + lko * 8) ^ ((row & 7) << 2);  // 16B-aligned
        f32x4 a0 = *(const f32x4*)&Af[fi];
        f32x4 a1 = *(const f32x4*)&Af[fi ^ 4];
        float av[8];
        *(f32x4*)&av[0] = a0;
        *(f32x4*)&av[4] = a1;
        bf16x8 ahi, alo;
        #pragma unroll
        for (int j = 0; j < 8; ++j) {
            uint ub = __float_as_uint(av[j]);
            float hf = __uint_as_float(ub & 0xFFFF0000u);
            float lf = av[j] - hf;
            ahi[j] = (short)(ub >> 16);
            alo[j] = (short)(__float_as_uint(lf) >> 16);
        }
        bf16x8 bfh[2], bfl[2];
        #pragma unroll
        for (int nf = 0; nf < 2; ++nf) {
            int col = wn * 32 + nf * 16 + lr;
            int ci = (col * 32 + lko * 8) ^ ((col & 7) << 3);        // ushort idx
            bfh[nf] = *(const bf16x8*)&Bh[i & 1][ci];
            bfl[nf] = *(const bf16x8*)&Bl[i & 1][ci];
        }
        #pragma unroll
        for (int nf = 0; nf < 2; ++nf) {
            acc[nf] = __builtin_amdgcn_mfma_f32_16x16x32_bf16(ahi, bfh[nf], acc[nf], 0, 0, 0);
            acc[nf] = __builtin_amdgcn_mfma_f32_16x16x32_bf16(alo, bfh[nf], acc[nf], 0, 0, 0);
            acc[nf] = __builtin_amdgcn_mfma_f32_16x16x32_bf16(ahi, bfl[nf], acc[nf], 0, 0, 0);
        }
        __syncthreads();
    }

    // C/D layout (m89-verified): col = lane&15, row = (lane>>4)*4 + reg
    #pragma unroll
    for (int r = 0; r < 4; ++r) {
        int orow = row0 + wm * 16 + lko * 4 + r;
        if (orow < N) {
            float dv = dinv[orow];
            #pragma unroll
            for (int nf = 0; nf < 2; ++nf)
                h1s[(size_t)orow * HID + wn * 32 + nf * 16 + lr] = f2bf(dv * acc[nf][r]);
        }
    }
}

// ---------------- fused agg1 + gemm2 (bf16 h1s gather, bf16 h2s out) ----------------
__global__ __launch_bounds__(256) void k_agg1g2(const ushort* __restrict__ h1s,
                                                const int* __restrict__ rowptr,
                                                const int* __restrict__ ssort,
                                                const float* __restrict__ dinv,
                                                const float* __restrict__ b1,
                                                const float* __restrict__ W2,
                                                ushort* __restrict__ h2s, int N) {
    __shared__ float wl[HID * OUTC];      // 2560 floats = 10.24 KB
    int t = threadIdx.x;
    #pragma unroll
    for (int q0 = 0; q0 < 3; ++q0) {
        int q = t + q0 * 256;
        if (q < 640) *(float4*)&wl[q * 4] = *(const float4*)&W2[q * 4];
    }
    __syncthreads();

    int lane = t & 63;
    int wq = t >> 6;
    int lc = lane < OUTC ? lane : 0;
    float bias = b1[lane];
    int nq = (N + 3) >> 2;

    for (int q = blockIdx.x; q < nq; q += gridDim.x) {
        int node = q * 4 + wq;
        if (node >= N) continue;
        float s0 = bf2f(h1s[(size_t)node * HID + lane]);   // self-loop term
        float sv[GDEPTH];
        #pragma unroll
        for (int k = 0; k < GDEPTH; ++k) sv[k] = 0.f;
        int eu = __builtin_amdgcn_readfirstlane(rowptr[node]);
        int endu = __builtin_amdgcn_readfirstlane(rowptr[node + 1]);
        for (int e = eu; e < endu; e += GDEPTH) {
            int raw[GDEPTH];
            #pragma unroll
            for (int k = 0; k < GDEPTH; ++k) raw[k] = ssort[e + k];  // scalar s_load path
            #pragma unroll
            for (int k = 0; k < GDEPTH; ++k) {
                int ix = (e + k < endu) ? raw[k] : raw[0];
                float v = bf2f(h1s[(size_t)ix * HID + lane]);
                sv[k] += (e + k < endu) ? v : 0.f;
            }
        }
        float s = s0;
        #pragma unroll
        for (int k = 0; k < GDEPTH; ++k) s += sv[k];
        float dv = dinv[node];
        float a = fmaxf(fmaf(dv, s, bias), 0.0f);
        // in-wave gemm2: h2[c] = sum_k a[k] * W2[k][c]
        float acc = 0.f;
        #pragma unroll
        for (int k = 0; k < HID; ++k) {
            float ak = __uint_as_float(__builtin_amdgcn_readlane(__float_as_uint(a), k));
            acc = fmaf(ak, wl[k * OUTC + lc], acc);
        }
        if (lane < OUTC) h2s[(size_t)node * OUTC + lane] = f2bf(dv * acc);
    }
}

// ---------------- agg2 + bias + softmax (bf16 h2s gather) ----------------
__global__ __launch_bounds__(256) void k_agg2(const ushort* __restrict__ h2s,
                                              const int* __restrict__ rowptr,
                                              const int* __restrict__ ssort,
                                              const float* __restrict__ dinv,
                                              const float* __restrict__ b2,
                                              float* __restrict__ out, int N) {
    int lane = threadIdx.x & 63;
    int node = blockIdx.x * 4 + (threadIdx.x >> 6);
    if (node >= N) return;
    bool act = lane < OUTC;
    int lc = act ? lane : 0;
    float s0 = bf2f(h2s[(size_t)node * OUTC + lc]);
    float sv[GDEPTH];
    #pragma unroll
    for (int k = 0; k < GDEPTH; ++k) sv[k] = 0.f;
    int eu = __builtin_amdgcn_readfirstlane(rowptr[node]);
    int endu = __builtin_amdgcn_readfirstlane(rowptr[node + 1]);
    for (int e = eu; e < endu; e += GDEPTH) {
        int raw[GDEPTH];
        #pragma unroll
        for (int k = 0; k < GDEPTH; ++k) raw[k] = ssort[e + k];
        #pragma unroll
        for (int k = 0; k < GDEPTH; ++k) {
            int ix = (e + k < endu) ? raw[k] : raw[0];
            float v = bf2f(h2s[(size_t)ix * OUTC + lc]);
            sv[k] += (e + k < endu) ? v : 0.f;
        }
    }
    float s = s0;
    #pragma unroll
    for (int k = 0; k < GDEPTH; ++k) s += sv[k];
    float v = act ? (dinv[node] * s + b2[lane]) : -INFINITY;
    float m = v;
    #pragma unroll
    for (int o = 32; o; o >>= 1) m = fmaxf(m, __shfl_xor(m, o));
    float p = act ? expf(v - m) : 0.0f;
    float su = p;
    #pragma unroll
    for (int o = 32; o; o >>= 1) su += __shfl_xor(su, o);
    if (act) out[(size_t)node * OUTC + lane] = p / su;
}

static inline size_t alignup(size_t v) { return (v + 255) & ~(size_t)255; }

extern "C" void kernel_launch(void* const* d_in, const int* in_sizes, int n_in,
                              void* d_out, int out_size, void* d_ws, size_t ws_size,
                              hipStream_t stream) {
    const float* x  = (const float*)d_in[0];
    const int*   ei = (const int*)d_in[1];
    const float* W1 = (const float*)d_in[2];
    const float* b1 = (const float*)d_in[3];
    const float* W2 = (const float*)d_in[4];
    const float* b2 = (const float*)d_in[5];

    const int N = in_sizes[0] / IN_C;
    const int E = in_sizes[1] / 2;
    const int* src = ei;
    const int* dst = ei + E;

    char* w = (char*)d_ws;
    int* cnt    = (int*)w;   w += alignup((size_t)N * 4);
    int* rank   = (int*)w;   w += alignup((size_t)E * 4 + 256);
    int* rowptr = (int*)w;   w += alignup((size_t)(N + 1) * 4);
    int* bsum   = (int*)w;   w += alignup(256 * 4);
    int* ssort  = (int*)w;   w += alignup((size_t)E * 4 + 256);  // +pad: scalar tail overreads
    float* dinv = (float*)w; w += alignup((size_t)N * 4);
    ushort* h1s = (ushort*)w; w += alignup((size_t)N * HID * 2);
    ushort* h2s = (ushort*)w; w += alignup((size_t)N * OUTC * 2);
    ushort* Bphi = (ushort*)w; w += alignup((size_t)HID * IN_C * 2);
    ushort* Bplo = (ushort*)w; w += alignup((size_t)HID * IN_C * 2);

    const int n4 = (N + 3) / 4;                 // int4 count covering cnt
    k_zero<<<(n4 + 255) / 256, 256, 0, stream>>>((int4*)cnt, n4);

    const int nb   = (N + 255) / 256;
    const int nbE2 = (E / 2 + 255) / 256;
    const int nbW  = (HID * IN_C + 255) / 256;
    k_histsplit<<<nbE2 + nbW, 256, 0, stream>>>(dst, E, cnt, rank, nbE2, W1, Bphi, Bplo);
    k_scan1 <<<nb, 256, 0, stream>>>(cnt, N, rowptr, bsum);
    k_scan23<<<nb, 256, 0, stream>>>(rowptr, bsum, cnt, dinv, N, E, nb);
    k_fill  <<<nbE2, 256, 0, stream>>>(src, dst, rank, E, rowptr, ssort);

    k_gemm1 <<<(N + 31) / 32, 256, 0, stream>>>(x, Bphi, Bplo, dinv, h1s, N);
    k_agg1g2<<<2048, 256, 0, stream>>>(h1s, rowptr, ssort, dinv, b1, W2, h2s, N);
    k_agg2  <<<(N + 3) / 4, 256, 0, stream>>>(h2s, rowptr, ssort, dinv, b2, (float*)d_out, N);
}

// Round 14
// 160.747 us; speedup vs baseline: 1.0734x; 1.0734x over previous
//
#include <hip/hip_runtime.h>
#include <math.h>

#define IN_C 512
#define HID  64
#define OUTC 40

typedef __attribute__((ext_vector_type(8))) short bf16x8;
typedef __attribute__((ext_vector_type(4))) float f32x4;

#define GDEPTH 16

__device__ __forceinline__ ushort f2bf(float f) {          // RNE
    uint u = __float_as_uint(f);
    u += 0x7FFFu + ((u >> 16) & 1u);
    return (ushort)(u >> 16);
}
__device__ __forceinline__ float bf2f(ushort s) {
    return __uint_as_float(((uint)s) << 16);
}

// async global->LDS, 16B per lane; lds base must be wave-uniform (HW adds lane*16)
__device__ __forceinline__ void gl_lds16(const void* g, void* l) {
    __builtin_amdgcn_global_load_lds(
        (const __attribute__((address_space(1))) void*)g,
        (__attribute__((address_space(3))) void*)l,
        16, 0, 0);
}

// ---------------- zero cnt ----------------
__global__ void k_zero(int4* __restrict__ p, int n4) {
    int i = blockIdx.x * blockDim.x + threadIdx.x;
    if (i < n4) p[i] = make_int4(0, 0, 0, 0);
}

// ---------------- histogram of dst + per-edge rank (+ W1 split, K-tiled + XOR-swizzled pack) ---
__global__ void k_histsplit(const int* __restrict__ dst, int E,
                            int* __restrict__ cnt, int* __restrict__ rank,
                            int nbE2,
                            const float* __restrict__ W,
                            ushort* __restrict__ hi, ushort* __restrict__ lo) {
    if (blockIdx.x < (unsigned)nbE2) {
        int i = (blockIdx.x * blockDim.x + threadIdx.x) * 2;
        if (i < E) {
            if (i + 1 < E) {
                int2 d = *(const int2*)&dst[i];
                int r0 = atomicAdd(&cnt[d.x], 1);
                int r1 = atomicAdd(&cnt[d.y], 1);
                *(int2*)&rank[i] = make_int2(r0, r1);
            } else {
                rank[i] = atomicAdd(&cnt[dst[i]], 1);
            }
        }
    } else {
        int i = (blockIdx.x - nbE2) * blockDim.x + threadIdx.x;   // over 64*512
        if (i >= HID * IN_C) return;
        int c = i >> 9, k = i & 511;
        float v = W[(size_t)k * HID + c];
        uint ub = __float_as_uint(v);
        uint hb = ub & 0xFFFF0000u;
        float lf = v - __uint_as_float(hb);
        int lb = c * 64 + (k & 31) * 2;                   // logical byte in tile
        int pb = lb ^ (((lb >> 6) & 7) << 4);             // swizzled byte
        int pidx = (k >> 5) * 2048 + (pb >> 1);           // ushort index
        hi[pidx] = (ushort)(ub >> 16);
        lo[pidx] = (ushort)(__float_as_uint(lf) >> 16);
    }
}

// ---------------- prefix scan ----------------
__global__ void k_scan1(const int* __restrict__ cnt, int N,
                        int* __restrict__ rowptr, int* __restrict__ bsum) {
    __shared__ int s[256];
    int t = threadIdx.x;
    int i = blockIdx.x * 256 + t;
    int v = (i < N) ? cnt[i] : 0;
    int x = v;
    s[t] = x; __syncthreads();
    #pragma unroll
    for (int o = 1; o < 256; o <<= 1) {
        int y = (t >= o) ? s[t - o] : 0;
        __syncthreads();
        x += y; s[t] = x;
        __syncthreads();
    }
    if (i < N) rowptr[i] = x - v;          // exclusive
    if (t == 255) bsum[blockIdx.x] = x;    // block total
}

// scan2+scan3 fused
__global__ void k_scan23(int* __restrict__ rowptr, const int* __restrict__ bsum,
                         const int* __restrict__ cnt, float* __restrict__ dinv,
                         int N, int E, int nb) {
    __shared__ int s[256];
    int t = threadIdx.x;
    int v = (t < nb) ? bsum[t] : 0;
    int x = v;
    s[t] = x; __syncthreads();
    #pragma unroll
    for (int o = 1; o < 256; o <<= 1) {
        int y = (t >= o) ? s[t - o] : 0;
        __syncthreads();
        x += y; s[t] = x;
        __syncthreads();
    }
    int bpre = (blockIdx.x > 0) ? s[blockIdx.x - 1] : 0;
    int i = blockIdx.x * 256 + t;
    if (i < N) {
        rowptr[i] += bpre;
        dinv[i] = rsqrtf(1.0f + (float)cnt[i]);   // self-loop => deg >= 1
        if (i == 0) rowptr[N] = E;
    }
}

// ---------------- GEMM1 (R12 structure, known-good) + fill merged; h1 split-written ----------
__global__ __launch_bounds__(256) void k_gemm1fill(
        const float* __restrict__ x,
        const ushort* __restrict__ Bphi, const ushort* __restrict__ Bplo,
        const float* __restrict__ dinv,
        ushort* __restrict__ h1a, ushort* __restrict__ h1b,
        int N, int nbG,
        const int* __restrict__ src, const int* __restrict__ dst,
        const int* __restrict__ rank, int E,
        const int* __restrict__ rowptr, int* __restrict__ ssort) {
    __shared__ float  Af[2][2048];
    __shared__ ushort Bh[2][2048], Bl[2][2048];

    if (blockIdx.x >= (unsigned)nbG) {
        // ---- fill path ----
        int i = ((blockIdx.x - nbG) * blockDim.x + threadIdx.x) * 2;
        if (i >= E) return;
        if (i + 1 < E) {
            int2 d = *(const int2*)&dst[i];
            int2 s = *(const int2*)&src[i];
            int2 r = *(const int2*)&rank[i];
            ssort[rowptr[d.x] + r.x] = s.x;
            ssort[rowptr[d.y] + r.y] = s.y;
        } else {
            ssort[rowptr[dst[i]] + rank[i]] = src[i];
        }
        return;
    }

    // ---- gemm path ----
    int t = threadIdx.x;
    int wid = t >> 6, lane = t & 63;
    int lr = lane & 15, lko = lane >> 4;
    int wm = wid >> 1, wn = wid & 1;
    int row0 = blockIdx.x * 64;

    int p0 = (wid * 64 + lane) * 16;
    int r0l = p0 >> 7;
    int o0 = p0 ^ ((r0l & 7) << 4);
    int g0 = row0 + r0l; if (g0 >= N) g0 = N - 1;
    const char* xsrc0 = (const char*)x + (size_t)g0 * 2048 + (o0 & 127);
    int p1 = p0 + 4096;
    int r1l = p1 >> 7;
    int o1 = p1 ^ ((r1l & 7) << 4);
    int g1 = row0 + r1l; if (g1 >= N) g1 = N - 1;
    const char* xsrc1 = (const char*)x + (size_t)g1 * 2048 + (o1 & 127);
    const char* bsrcH = (const char*)Bphi + (size_t)(wid * 64 + lane) * 16;
    const char* bsrcL = (const char*)Bplo + (size_t)(wid * 64 + lane) * 16;

    f32x4 acc[2][2] = {};

    auto stage = [&](int tile, int b) {
        gl_lds16(xsrc0 + (size_t)tile * 128, (char*)&Af[b][0] + wid * 1024);
        gl_lds16(xsrc1 + (size_t)tile * 128, (char*)&Af[b][0] + 4096 + wid * 1024);
        gl_lds16(bsrcH + (size_t)tile * 4096, (char*)&Bh[b][0] + wid * 1024);
        gl_lds16(bsrcL + (size_t)tile * 4096, (char*)&Bl[b][0] + wid * 1024);
    };
    auto compute = [&](int b) {
        bf16x8 afh[2], afl[2], bfh[2], bfl[2];
        #pragma unroll
        for (int mf = 0; mf < 2; ++mf) {
            int row = wm * 32 + mf * 16 + lr;
            int fi = (row * 32 + lko * 8) ^ ((row & 7) << 2);
            f32x4 a0 = *(const f32x4*)&Af[b][fi];
            f32x4 a1 = *(const f32x4*)&Af[b][fi ^ 4];
            float av[8];
            *(f32x4*)&av[0] = a0;
            *(f32x4*)&av[4] = a1;
            #pragma unroll
            for (int j = 0; j < 8; ++j) {
                uint ub = __float_as_uint(av[j]);
                float hf = __uint_as_float(ub & 0xFFFF0000u);
                float lf = av[j] - hf;
                afh[mf][j] = (short)(ub >> 16);
                afl[mf][j] = (short)(__float_as_uint(lf) >> 16);
            }
        }
        #pragma unroll
        for (int nf = 0; nf < 2; ++nf) {
            int col = wn * 32 + nf * 16 + lr;
            int ci = (col * 32 + lko * 8) ^ ((col & 7) << 3);
            bfh[nf] = *(const bf16x8*)&Bh[b][ci];
            bfl[nf] = *(const bf16x8*)&Bl[b][ci];
        }
        #pragma unroll
        for (int mf = 0; mf < 2; ++mf)
            #pragma unroll
            for (int nf = 0; nf < 2; ++nf) {
                acc[mf][nf] = __builtin_amdgcn_mfma_f32_16x16x32_bf16(afh[mf], bfh[nf], acc[mf][nf], 0, 0, 0);
                acc[mf][nf] = __builtin_amdgcn_mfma_f32_16x16x32_bf16(afl[mf], bfh[nf], acc[mf][nf], 0, 0, 0);
                acc[mf][nf] = __builtin_amdgcn_mfma_f32_16x16x32_bf16(afh[mf], bfl[nf], acc[mf][nf], 0, 0, 0);
            }
    };

    stage(0, 0);
    __syncthreads();

    #pragma unroll
    for (int i = 0; i < 16; ++i) {
        if (i < 15) stage(i + 1, (i + 1) & 1);
        compute(i & 1);
        __syncthreads();
    }

    // write to channel-half buffer (wn selects half; ch-in-half = nf*16+lr)
    ushort* hb = wn ? h1b : h1a;
    #pragma unroll
    for (int mf = 0; mf < 2; ++mf)
        #pragma unroll
        for (int r = 0; r < 4; ++r) {
            int orow = row0 + wm * 32 + mf * 16 + lko * 4 + r;
            if (orow < N) {
                float dv = dinv[orow];
                #pragma unroll
                for (int nf = 0; nf < 2; ++nf)
                    hb[(size_t)orow * 32 + nf * 16 + lr] = f2bf(dv * acc[mf][nf][r]);
            }
        }
}

// ---------------- agg1 half-pass: 32-lane group per node, L2-resident 3.2MB gather set -------
// a1f[n*64 + half*32 + ch] = relu(dinv*(h1x[n] + sum_e h1x[src]) + b1[half*32+ch])
__global__ __launch_bounds__(256) void k_aggh(const ushort* __restrict__ h1x,
                                              const int* __restrict__ rowptr,
                                              const int* __restrict__ ssort,
                                              const float* __restrict__ dinv,
                                              const float* __restrict__ b1,
                                              ushort* __restrict__ a1f,
                                              int N, int half) {
    int t = blockIdx.x * blockDim.x + threadIdx.x;
    int node = t >> 5;                 // one 32-lane group per node
    int ch = t & 31;
    if (node >= N) return;
    float s0 = bf2f(h1x[(size_t)node * 32 + ch]);
    float sv[GDEPTH];
    #pragma unroll
    for (int k = 0; k < GDEPTH; ++k) sv[k] = 0.f;
    int elo = rowptr[node], ehi = rowptr[node + 1];    // uniform within group
    for (int e = elo; e < ehi; e += GDEPTH) {
        int raw[GDEPTH];
        #pragma unroll
        for (int k = 0; k < GDEPTH; ++k) raw[k] = ssort[e + k];
        #pragma unroll
        for (int k = 0; k < GDEPTH; ++k) {
            int ix = (e + k < ehi) ? raw[k] : raw[0];
            float v = bf2f(h1x[(size_t)ix * 32 + ch]);
            sv[k] += (e + k < ehi) ? v : 0.f;
        }
    }
    float s = s0;
    #pragma unroll
    for (int k = 0; k < GDEPTH; ++k) s += sv[k];
    float a = fmaxf(fmaf(dinv[node], s, b1[half * 32 + ch]), 0.0f);
    __builtin_nontemporal_store(f2bf(a), &a1f[(size_t)node * 64 + half * 32 + ch]);
}

// ---------------- gemm2: h2s[n][c] = dinv[n] * sum_k a1f[n][k] * W2[k][c] ----------------
__global__ __launch_bounds__(256) void k_gemm2b(const ushort* __restrict__ a1f,
                                                const float* __restrict__ dinv,
                                                const float* __restrict__ W2,
                                                ushort* __restrict__ h2s, int N) {
    __shared__ float wl[HID * OUTC];
    int t = threadIdx.x;
    #pragma unroll
    for (int q0 = 0; q0 < 3; ++q0) {
        int q = t + q0 * 256;
        if (q < 640) *(float4*)&wl[q * 4] = *(const float4*)&W2[q * 4];
    }
    __syncthreads();
    int lane = t & 63;
    int node = blockIdx.x * 4 + (t >> 6);
    if (node >= N) return;
    int lc = lane < OUTC ? lane : 0;
    float a = bf2f(a1f[(size_t)node * 64 + lane]);
    float acc = 0.f;
    #pragma unroll
    for (int k = 0; k < HID; ++k) {
        float ak = __uint_as_float(__builtin_amdgcn_readlane(__float_as_uint(a), k));
        acc = fmaf(ak, wl[k * OUTC + lc], acc);
    }
    if (lane < OUTC) h2s[(size_t)node * OUTC + lane] = f2bf(dinv[node] * acc);
}

// ---------------- agg2 + bias + softmax (bf16 h2s gather) ----------------
__global__ __launch_bounds__(256) void k_agg2(const ushort* __restrict__ h2s,
                                              const int* __restrict__ rowptr,
                                              const int* __restrict__ ssort,
                                              const float* __restrict__ dinv,
                                              const float* __restrict__ b2,
                                              float* __restrict__ out, int N) {
    int lane = threadIdx.x & 63;
    int node = blockIdx.x * 4 + (threadIdx.x >> 6);
    if (node >= N) return;
    bool act = lane < OUTC;
    int lc = act ? lane : 0;
    float s0 = bf2f(h2s[(size_t)node * OUTC + lc]);
    float sv[GDEPTH];
    #pragma unroll
    for (int k = 0; k < GDEPTH; ++k) sv[k] = 0.f;
    int eu = __builtin_amdgcn_readfirstlane(rowptr[node]);
    int endu = __builtin_amdgcn_readfirstlane(rowptr[node + 1]);
    for (int e = eu; e < endu; e += GDEPTH) {
        int raw[GDEPTH];
        #pragma unroll
        for (int k = 0; k < GDEPTH; ++k) raw[k] = ssort[e + k];
        #pragma unroll
        for (int k = 0; k < GDEPTH; ++k) {
            int ix = (e + k < endu) ? raw[k] : raw[0];
            float v = bf2f(h2s[(size_t)ix * OUTC + lc]);
            sv[k] += (e + k < endu) ? v : 0.f;
        }
    }
    float s = s0;
    #pragma unroll
    for (int k = 0; k < GDEPTH; ++k) s += sv[k];
    float v = act ? (dinv[node] * s + b2[lane]) : -INFINITY;
    float m = v;
    #pragma unroll
    for (int o = 32; o; o >>= 1) m = fmaxf(m, __shfl_xor(m, o));
    float p = act ? expf(v - m) : 0.0f;
    float su = p;
    #pragma unroll
    for (int o = 32; o; o >>= 1) su += __shfl_xor(su, o);
    if (act) out[(size_t)node * OUTC + lane] = p / su;
}

static inline size_t alignup(size_t v) { return (v + 255) & ~(size_t)255; }

extern "C" void kernel_launch(void* const* d_in, const int* in_sizes, int n_in,
                              void* d_out, int out_size, void* d_ws, size_t ws_size,
                              hipStream_t stream) {
    const float* x  = (const float*)d_in[0];
    const int*   ei = (const int*)d_in[1];
    const float* W1 = (const float*)d_in[2];
    const float* b1 = (const float*)d_in[3];
    const float* W2 = (const float*)d_in[4];
    const float* b2 = (const float*)d_in[5];

    const int N = in_sizes[0] / IN_C;
    const int E = in_sizes[1] / 2;
    const int* src = ei;
    const int* dst = ei + E;

    char* w = (char*)d_ws;
    int* cnt    = (int*)w;   w += alignup((size_t)N * 4);
    int* rank   = (int*)w;   w += alignup((size_t)E * 4 + 256);
    int* rowptr = (int*)w;   w += alignup((size_t)(N + 1) * 4);
    int* bsum   = (int*)w;   w += alignup(256 * 4);
    int* ssort  = (int*)w;   w += alignup((size_t)E * 4 + 256);
    float* dinv = (float*)w; w += alignup((size_t)N * 4);
    ushort* h1a = (ushort*)w; w += alignup((size_t)N * 32 * 2);
    ushort* h1b = (ushort*)w; w += alignup((size_t)N * 32 * 2);
    ushort* a1f = (ushort*)w; w += alignup((size_t)N * HID * 2);
    ushort* h2s = (ushort*)w; w += alignup((size_t)N * OUTC * 2);
    ushort* Bphi = (ushort*)w; w += alignup((size_t)HID * IN_C * 2);
    ushort* Bplo = (ushort*)w; w += alignup((size_t)HID * IN_C * 2);

    const int n4 = (N + 3) / 4;
    k_zero<<<(n4 + 255) / 256, 256, 0, stream>>>((int4*)cnt, n4);

    const int nb   = (N + 255) / 256;
    const int nbE2 = (E / 2 + 255) / 256;
    const int nbW  = (HID * IN_C + 255) / 256;
    k_histsplit<<<nbE2 + nbW, 256, 0, stream>>>(dst, E, cnt, rank, nbE2, W1, Bphi, Bplo);
    k_scan1 <<<nb, 256, 0, stream>>>(cnt, N, rowptr, bsum);
    k_scan23<<<nb, 256, 0, stream>>>(rowptr, bsum, cnt, dinv, N, E, nb);

    const int nbG = (N + 63) / 64;
    k_gemm1fill<<<nbG + nbE2, 256, 0, stream>>>(x, Bphi, Bplo, dinv, h1a, h1b, N, nbG,
                                                src, dst, rank, E, rowptr, ssort);
    const int nbA = ((size_t)N * 32 + 255) / 256;
    k_aggh <<<nbA, 256, 0, stream>>>(h1a, rowptr, ssort, dinv, b1, a1f, N, 0);
    k_aggh <<<nbA, 256, 0, stream>>>(h1b, rowptr, ssort, dinv, b1, a1f, N, 1);
    k_gemm2b<<<(N + 3) / 4, 256, 0, stream>>>(a1f, dinv, W2, h2s, N);
    k_agg2 <<<(N + 3) / 4, 256, 0, stream>>>(h2s, rowptr, ssort, dinv, b2, (float*)d_out, N);
}

// Round 15
// 150.924 us; speedup vs baseline: 1.1433x; 1.0651x over previous
//
#include <hip/hip_runtime.h>
#include <math.h>

#define IN_C 512
#define HID  64
#define OUTC 40

typedef __attribute__((ext_vector_type(8))) short bf16x8;
typedef __attribute__((ext_vector_type(4))) float f32x4;

#define GDEPTH 16

__device__ __forceinline__ ushort f2bf(float f) {          // RNE
    uint u = __float_as_uint(f);
    u += 0x7FFFu + ((u >> 16) & 1u);
    return (ushort)(u >> 16);
}
__device__ __forceinline__ float bf2f(ushort s) {
    return __uint_as_float(((uint)s) << 16);
}

// async global->LDS, 16B per lane; lds base must be wave-uniform (HW adds lane*16)
__device__ __forceinline__ void gl_lds16(const void* g, void* l) {
    __builtin_amdgcn_global_load_lds(
        (const __attribute__((address_space(1))) void*)g,
        (__attribute__((address_space(3))) void*)l,
        16, 0, 0);
}

// ---------------- zero cnt ----------------
__global__ void k_zero(int4* __restrict__ p, int n4) {
    int i = blockIdx.x * blockDim.x + threadIdx.x;
    if (i < n4) p[i] = make_int4(0, 0, 0, 0);
}

// ---------------- histogram of dst + per-edge rank (+ W1 split, K-tiled + XOR-swizzled pack) ---
__global__ void k_histsplit(const int* __restrict__ dst, int E,
                            int* __restrict__ cnt, int* __restrict__ rank,
                            int nbE2,
                            const float* __restrict__ W,
                            ushort* __restrict__ hi, ushort* __restrict__ lo) {
    if (blockIdx.x < (unsigned)nbE2) {
        int i = (blockIdx.x * blockDim.x + threadIdx.x) * 2;
        if (i < E) {
            if (i + 1 < E) {
                int2 d = *(const int2*)&dst[i];
                int r0 = atomicAdd(&cnt[d.x], 1);
                int r1 = atomicAdd(&cnt[d.y], 1);
                *(int2*)&rank[i] = make_int2(r0, r1);
            } else {
                rank[i] = atomicAdd(&cnt[dst[i]], 1);
            }
        }
    } else {
        int i = (blockIdx.x - nbE2) * blockDim.x + threadIdx.x;   // over 64*512
        if (i >= HID * IN_C) return;
        int c = i >> 9, k = i & 511;
        float v = W[(size_t)k * HID + c];
        uint ub = __float_as_uint(v);
        uint hb = ub & 0xFFFF0000u;
        float lf = v - __uint_as_float(hb);
        int lb = c * 64 + (k & 31) * 2;                   // logical byte in tile
        int pb = lb ^ (((lb >> 6) & 7) << 4);             // swizzled byte
        int pidx = (k >> 5) * 2048 + (pb >> 1);           // ushort index
        hi[pidx] = (ushort)(ub >> 16);
        lo[pidx] = (ushort)(__float_as_uint(lf) >> 16);
    }
}

// ---------------- prefix scan ----------------
__global__ void k_scan1(const int* __restrict__ cnt, int N,
                        int* __restrict__ rowptr, int* __restrict__ bsum) {
    __shared__ int s[256];
    int t = threadIdx.x;
    int i = blockIdx.x * 256 + t;
    int v = (i < N) ? cnt[i] : 0;
    int x = v;
    s[t] = x; __syncthreads();
    #pragma unroll
    for (int o = 1; o < 256; o <<= 1) {
        int y = (t >= o) ? s[t - o] : 0;
        __syncthreads();
        x += y; s[t] = x;
        __syncthreads();
    }
    if (i < N) rowptr[i] = x - v;          // exclusive
    if (t == 255) bsum[blockIdx.x] = x;    // block total
}

// scan2+scan3 fused
__global__ void k_scan23(int* __restrict__ rowptr, const int* __restrict__ bsum,
                         const int* __restrict__ cnt, float* __restrict__ dinv,
                         int N, int E, int nb) {
    __shared__ int s[256];
    int t = threadIdx.x;
    int v = (t < nb) ? bsum[t] : 0;
    int x = v;
    s[t] = x; __syncthreads();
    #pragma unroll
    for (int o = 1; o < 256; o <<= 1) {
        int y = (t >= o) ? s[t - o] : 0;
        __syncthreads();
        x += y; s[t] = x;
        __syncthreads();
    }
    int bpre = (blockIdx.x > 0) ? s[blockIdx.x - 1] : 0;
    int i = blockIdx.x * 256 + t;
    if (i < N) {
        rowptr[i] += bpre;
        dinv[i] = rsqrtf(1.0f + (float)cnt[i]);   // self-loop => deg >= 1
        if (i == 0) rowptr[N] = E;
    }
}

// ---------------- GEMM1 (counted-vmcnt pipeline, T3/T4) + fill merged ----------------
// 3 LDS buffers, 2-deep prefetch. Per iter: wait vmcnt(4) (tile i landed,
// tile i+1 still in flight), raw s_barrier, issue stage(i+2), compute(i).
// Never drains vmcnt to 0 in the loop -> loads stay in flight across barriers.
__global__ __launch_bounds__(256) void k_gemm1fill(
        const float* __restrict__ x,
        const ushort* __restrict__ Bphi, const ushort* __restrict__ Bplo,
        const float* __restrict__ dinv, ushort* __restrict__ h1s,
        int N, int nbG,
        const int* __restrict__ src, const int* __restrict__ dst,
        const int* __restrict__ rank, int E,
        const int* __restrict__ rowptr, int* __restrict__ ssort) {
    __shared__ float  Af[3][2048];                 // 3 x 8KB
    __shared__ ushort Bh[3][2048], Bl[3][2048];    // 3 x (4KB + 4KB)

    if (blockIdx.x >= (unsigned)nbG) {
        // ---- fill path ----
        int i = ((blockIdx.x - nbG) * blockDim.x + threadIdx.x) * 2;
        if (i >= E) return;
        if (i + 1 < E) {
            int2 d = *(const int2*)&dst[i];
            int2 s = *(const int2*)&src[i];
            int2 r = *(const int2*)&rank[i];
            ssort[rowptr[d.x] + r.x] = s.x;
            ssort[rowptr[d.y] + r.y] = s.y;
        } else {
            ssort[rowptr[dst[i]] + rank[i]] = src[i];
        }
        return;
    }

    // ---- gemm path ----
    int t = threadIdx.x;
    int wid = t >> 6, lane = t & 63;
    int lr = lane & 15, lko = lane >> 4;
    int wm = wid >> 1, wn = wid & 1;
    int row0 = blockIdx.x * 64;

    int p0 = (wid * 64 + lane) * 16;
    int r0l = p0 >> 7;
    int o0 = p0 ^ ((r0l & 7) << 4);
    int g0 = row0 + r0l; if (g0 >= N) g0 = N - 1;
    const char* xsrc0 = (const char*)x + (size_t)g0 * 2048 + (o0 & 127);
    int p1 = p0 + 4096;
    int r1l = p1 >> 7;
    int o1 = p1 ^ ((r1l & 7) << 4);
    int g1 = row0 + r1l; if (g1 >= N) g1 = N - 1;
    const char* xsrc1 = (const char*)x + (size_t)g1 * 2048 + (o1 & 127);
    const char* bsrcH = (const char*)Bphi + (size_t)(wid * 64 + lane) * 16;
    const char* bsrcL = (const char*)Bplo + (size_t)(wid * 64 + lane) * 16;

    f32x4 acc[2][2] = {};

    auto stage = [&](int tile, int b) {            // 4 gl_lds16 per wave -> vmcnt +4
        gl_lds16(xsrc0 + (size_t)tile * 128, (char*)&Af[b][0] + wid * 1024);
        gl_lds16(xsrc1 + (size_t)tile * 128, (char*)&Af[b][0] + 4096 + wid * 1024);
        gl_lds16(bsrcH + (size_t)tile * 4096, (char*)&Bh[b][0] + wid * 1024);
        gl_lds16(bsrcL + (size_t)tile * 4096, (char*)&Bl[b][0] + wid * 1024);
    };
    auto compute = [&](int b) {
        bf16x8 afh[2], afl[2], bfh[2], bfl[2];
        #pragma unroll
        for (int mf = 0; mf < 2; ++mf) {
            int row = wm * 32 + mf * 16 + lr;
            int fi = (row * 32 + lko * 8) ^ ((row & 7) << 2);
            f32x4 a0 = *(const f32x4*)&Af[b][fi];
            f32x4 a1 = *(const f32x4*)&Af[b][fi ^ 4];
            float av[8];
            *(f32x4*)&av[0] = a0;
            *(f32x4*)&av[4] = a1;
            #pragma unroll
            for (int j = 0; j < 8; ++j) {
                uint ub = __float_as_uint(av[j]);
                float hf = __uint_as_float(ub & 0xFFFF0000u);
                float lf = av[j] - hf;
                afh[mf][j] = (short)(ub >> 16);
                afl[mf][j] = (short)(__float_as_uint(lf) >> 16);
            }
        }
        #pragma unroll
        for (int nf = 0; nf < 2; ++nf) {
            int col = wn * 32 + nf * 16 + lr;
            int ci = (col * 32 + lko * 8) ^ ((col & 7) << 3);
            bfh[nf] = *(const bf16x8*)&Bh[b][ci];
            bfl[nf] = *(const bf16x8*)&Bl[b][ci];
        }
        #pragma unroll
        for (int mf = 0; mf < 2; ++mf)
            #pragma unroll
            for (int nf = 0; nf < 2; ++nf) {
                acc[mf][nf] = __builtin_amdgcn_mfma_f32_16x16x32_bf16(afh[mf], bfh[nf], acc[mf][nf], 0, 0, 0);
                acc[mf][nf] = __builtin_amdgcn_mfma_f32_16x16x32_bf16(afl[mf], bfh[nf], acc[mf][nf], 0, 0, 0);
                acc[mf][nf] = __builtin_amdgcn_mfma_f32_16x16x32_bf16(afh[mf], bfl[nf], acc[mf][nf], 0, 0, 0);
            }
    };

    stage(0, 0);
    stage(1, 1);

    #pragma unroll
    for (int i = 0; i < 16; ++i) {
        if (i < 15) {
            asm volatile("s_waitcnt vmcnt(4)" ::: "memory");   // tile i landed; i+1 in flight
        } else {
            asm volatile("s_waitcnt vmcnt(0)" ::: "memory");   // last tile: drain
        }
        __builtin_amdgcn_sched_barrier(0);
        __builtin_amdgcn_s_barrier();                           // all waves' tile-i writes visible
        __builtin_amdgcn_sched_barrier(0);
        if (i < 14) stage(i + 2, (i + 2) % 3);                  // overwrites buf (i-1)%3: all done reading
        compute(i % 3);
    }

    // C/D layout (m89-verified): col = lane&15, row = (lane>>4)*4 + reg
    #pragma unroll
    for (int mf = 0; mf < 2; ++mf)
        #pragma unroll
        for (int r = 0; r < 4; ++r) {
            int orow = row0 + wm * 32 + mf * 16 + lko * 4 + r;
            if (orow < N) {
                float dv = dinv[orow];
                #pragma unroll
                for (int nf = 0; nf < 2; ++nf)
                    h1s[(size_t)orow * HID + wn * 32 + nf * 16 + lr] = f2bf(dv * acc[mf][nf][r]);
            }
        }
}

// ---------------- fused agg1 + gemm2 (bf16 h1s gather, bf16 h2s out) ----------------
__global__ __launch_bounds__(256) void k_agg1g2(const ushort* __restrict__ h1s,
                                                const int* __restrict__ rowptr,
                                                const int* __restrict__ ssort,
                                                const float* __restrict__ dinv,
                                                const float* __restrict__ b1,
                                                const float* __restrict__ W2,
                                                ushort* __restrict__ h2s, int N) {
    __shared__ float wl[HID * OUTC];      // 2560 floats = 10.24 KB
    int t = threadIdx.x;
    #pragma unroll
    for (int q0 = 0; q0 < 3; ++q0) {
        int q = t + q0 * 256;
        if (q < 640) *(float4*)&wl[q * 4] = *(const float4*)&W2[q * 4];
    }
    __syncthreads();

    int lane = t & 63;
    int wq = t >> 6;
    int lc = lane < OUTC ? lane : 0;
    float bias = b1[lane];
    int nq = (N + 3) >> 2;

    for (int q = blockIdx.x; q < nq; q += gridDim.x) {
        int node = q * 4 + wq;
        if (node >= N) continue;
        float s0 = bf2f(h1s[(size_t)node * HID + lane]);   // self-loop term
        float sv[GDEPTH];
        #pragma unroll
        for (int k = 0; k < GDEPTH; ++k) sv[k] = 0.f;
        int eu = __builtin_amdgcn_readfirstlane(rowptr[node]);
        int endu = __builtin_amdgcn_readfirstlane(rowptr[node + 1]);
        for (int e = eu; e < endu; e += GDEPTH) {
            int raw[GDEPTH];
            #pragma unroll
            for (int k = 0; k < GDEPTH; ++k) raw[k] = ssort[e + k];  // scalar s_load path
            #pragma unroll
            for (int k = 0; k < GDEPTH; ++k) {
                int ix = (e + k < endu) ? raw[k] : raw[0];
                float v = bf2f(h1s[(size_t)ix * HID + lane]);
                sv[k] += (e + k < endu) ? v : 0.f;
            }
        }
        float s = s0;
        #pragma unroll
        for (int k = 0; k < GDEPTH; ++k) s += sv[k];
        float dv = dinv[node];
        float a = fmaxf(fmaf(dv, s, bias), 0.0f);
        // in-wave gemm2: h2[c] = sum_k a[k] * W2[k][c]
        float acc = 0.f;
        #pragma unroll
        for (int k = 0; k < HID; ++k) {
            float ak = __uint_as_float(__builtin_amdgcn_readlane(__float_as_uint(a), k));
            acc = fmaf(ak, wl[k * OUTC + lc], acc);
        }
        if (lane < OUTC) h2s[(size_t)node * OUTC + lane] = f2bf(dv * acc);
    }
}

// ---------------- agg2 + bias + softmax (bf16 h2s gather) ----------------
__global__ __launch_bounds__(256) void k_agg2(const ushort* __restrict__ h2s,
                                              const int* __restrict__ rowptr,
                                              const int* __restrict__ ssort,
                                              const float* __restrict__ dinv,
                                              const float* __restrict__ b2,
                                              float* __restrict__ out, int N) {
    int lane = threadIdx.x & 63;
    int node = blockIdx.x * 4 + (threadIdx.x >> 6);
    if (node >= N) return;
    bool act = lane < OUTC;
    int lc = act ? lane : 0;
    float s0 = bf2f(h2s[(size_t)node * OUTC + lc]);
    float sv[GDEPTH];
    #pragma unroll
    for (int k = 0; k < GDEPTH; ++k) sv[k] = 0.f;
    int eu = __builtin_amdgcn_readfirstlane(rowptr[node]);
    int endu = __builtin_amdgcn_readfirstlane(rowptr[node + 1]);
    for (int e = eu; e < endu; e += GDEPTH) {
        int raw[GDEPTH];
        #pragma unroll
        for (int k = 0; k < GDEPTH; ++k) raw[k] = ssort[e + k];
        #pragma unroll
        for (int k = 0; k < GDEPTH; ++k) {
            int ix = (e + k < endu) ? raw[k] : raw[0];
            float v = bf2f(h2s[(size_t)ix * OUTC + lc]);
            sv[k] += (e + k < endu) ? v : 0.f;
        }
    }
    float s = s0;
    #pragma unroll
    for (int k = 0; k < GDEPTH; ++k) s += sv[k];
    float v = act ? (dinv[node] * s + b2[lane]) : -INFINITY;
    float m = v;
    #pragma unroll
    for (int o = 32; o; o >>= 1) m = fmaxf(m, __shfl_xor(m, o));
    float p = act ? expf(v - m) : 0.0f;
    float su = p;
    #pragma unroll
    for (int o = 32; o; o >>= 1) su += __shfl_xor(su, o);
    if (act) out[(size_t)node * OUTC + lane] = p / su;
}

static inline size_t alignup(size_t v) { return (v + 255) & ~(size_t)255; }

extern "C" void kernel_launch(void* const* d_in, const int* in_sizes, int n_in,
                              void* d_out, int out_size, void* d_ws, size_t ws_size,
                              hipStream_t stream) {
    const float* x  = (const float*)d_in[0];
    const int*   ei = (const int*)d_in[1];
    const float* W1 = (const float*)d_in[2];
    const float* b1 = (const float*)d_in[3];
    const float* W2 = (const float*)d_in[4];
    const float* b2 = (const float*)d_in[5];

    const int N = in_sizes[0] / IN_C;
    const int E = in_sizes[1] / 2;
    const int* src = ei;
    const int* dst = ei + E;

    char* w = (char*)d_ws;
    int* cnt    = (int*)w;   w += alignup((size_t)N * 4);
    int* rank   = (int*)w;   w += alignup((size_t)E * 4 + 256);
    int* rowptr = (int*)w;   w += alignup((size_t)(N + 1) * 4);
    int* bsum   = (int*)w;   w += alignup(256 * 4);
    int* ssort  = (int*)w;   w += alignup((size_t)E * 4 + 256);  // +pad: scalar tail overreads
    float* dinv = (float*)w; w += alignup((size_t)N * 4);
    ushort* h1s = (ushort*)w; w += alignup((size_t)N * HID * 2);
    ushort* h2s = (ushort*)w; w += alignup((size_t)N * OUTC * 2);
    ushort* Bphi = (ushort*)w; w += alignup((size_t)HID * IN_C * 2);
    ushort* Bplo = (ushort*)w; w += alignup((size_t)HID * IN_C * 2);

    const int n4 = (N + 3) / 4;
    k_zero<<<(n4 + 255) / 256, 256, 0, stream>>>((int4*)cnt, n4);

    const int nb   = (N + 255) / 256;
    const int nbE2 = (E / 2 + 255) / 256;
    const int nbW  = (HID * IN_C + 255) / 256;
    k_histsplit<<<nbE2 + nbW, 256, 0, stream>>>(dst, E, cnt, rank, nbE2, W1, Bphi, Bplo);
    k_scan1 <<<nb, 256, 0, stream>>>(cnt, N, rowptr, bsum);
    k_scan23<<<nb, 256, 0, stream>>>(rowptr, bsum, cnt, dinv, N, E, nb);

    const int nbG = (N + 63) / 64;
    k_gemm1fill<<<nbG + nbE2, 256, 0, stream>>>(x, Bphi, Bplo, dinv, h1s, N, nbG,
                                                src, dst, rank, E, rowptr, ssort);
    k_agg1g2<<<2048, 256, 0, stream>>>(h1s, rowptr, ssort, dinv, b1, W2, h2s, N);
    k_agg2  <<<(N + 3) / 4, 256, 0, stream>>>(h2s, rowptr, ssort, dinv, b2, (float*)d_out, N);
}

// Round 16
// 147.680 us; speedup vs baseline: 1.1684x; 1.0220x over previous
//
#include <hip/hip_runtime.h>
#include <math.h>

#define IN_C 512
#define HID  64
#define OUTC 40

typedef __attribute__((ext_vector_type(8))) short bf16x8;
typedef __attribute__((ext_vector_type(4))) float f32x4;

#define GDEPTH 16

__device__ __forceinline__ ushort f2bf(float f) {          // RNE
    uint u = __float_as_uint(f);
    u += 0x7FFFu + ((u >> 16) & 1u);
    return (ushort)(u >> 16);
}
__device__ __forceinline__ float bf2f(ushort s) {
    return __uint_as_float(((uint)s) << 16);
}

// async global->LDS, 16B per lane; lds base must be wave-uniform (HW adds lane*16)
__device__ __forceinline__ void gl_lds16(const void* g, void* l) {
    __builtin_amdgcn_global_load_lds(
        (const __attribute__((address_space(1))) void*)g,
        (__attribute__((address_space(3))) void*)l,
        16, 0, 0);
}

// ---------------- zero cnt ----------------
__global__ void k_zero(int4* __restrict__ p, int n4) {
    int i = blockIdx.x * blockDim.x + threadIdx.x;
    if (i < n4) p[i] = make_int4(0, 0, 0, 0);
}

// ---------------- histogram of dst + per-edge rank (+ W1 split, K-tiled + XOR-swizzled pack) ---
__global__ void k_histsplit(const int* __restrict__ dst, int E,
                            int* __restrict__ cnt, int* __restrict__ rank,
                            int nbE2,
                            const float* __restrict__ W,
                            ushort* __restrict__ hi, ushort* __restrict__ lo) {
    if (blockIdx.x < (unsigned)nbE2) {
        int i = (blockIdx.x * blockDim.x + threadIdx.x) * 2;
        if (i < E) {
            if (i + 1 < E) {
                int2 d = *(const int2*)&dst[i];
                int r0 = atomicAdd(&cnt[d.x], 1);
                int r1 = atomicAdd(&cnt[d.y], 1);
                *(int2*)&rank[i] = make_int2(r0, r1);
            } else {
                rank[i] = atomicAdd(&cnt[dst[i]], 1);
            }
        }
    } else {
        int i = (blockIdx.x - nbE2) * blockDim.x + threadIdx.x;   // over 64*512
        if (i >= HID * IN_C) return;
        int c = i >> 9, k = i & 511;
        float v = W[(size_t)k * HID + c];
        uint ub = __float_as_uint(v);
        uint hb = ub & 0xFFFF0000u;
        float lf = v - __uint_as_float(hb);
        int lb = c * 64 + (k & 31) * 2;                   // logical byte in tile
        int pb = lb ^ (((lb >> 6) & 7) << 4);             // swizzled byte
        int pidx = (k >> 5) * 2048 + (pb >> 1);           // ushort index
        hi[pidx] = (ushort)(ub >> 16);
        lo[pidx] = (ushort)(__float_as_uint(lf) >> 16);
    }
}

// ---------------- prefix scan ----------------
__global__ void k_scan1(const int* __restrict__ cnt, int N,
                        int* __restrict__ rowptr, int* __restrict__ bsum) {
    __shared__ int s[256];
    int t = threadIdx.x;
    int i = blockIdx.x * 256 + t;
    int v = (i < N) ? cnt[i] : 0;
    int x = v;
    s[t] = x; __syncthreads();
    #pragma unroll
    for (int o = 1; o < 256; o <<= 1) {
        int y = (t >= o) ? s[t - o] : 0;
        __syncthreads();
        x += y; s[t] = x;
        __syncthreads();
    }
    if (i < N) rowptr[i] = x - v;          // exclusive
    if (t == 255) bsum[blockIdx.x] = x;    // block total
}

// scan2+scan3 fused
__global__ void k_scan23(int* __restrict__ rowptr, const int* __restrict__ bsum,
                         const int* __restrict__ cnt, float* __restrict__ dinv,
                         int N, int E, int nb) {
    __shared__ int s[256];
    int t = threadIdx.x;
    int v = (t < nb) ? bsum[t] : 0;
    int x = v;
    s[t] = x; __syncthreads();
    #pragma unroll
    for (int o = 1; o < 256; o <<= 1) {
        int y = (t >= o) ? s[t - o] : 0;
        __syncthreads();
        x += y; s[t] = x;
        __syncthreads();
    }
    int bpre = (blockIdx.x > 0) ? s[blockIdx.x - 1] : 0;
    int i = blockIdx.x * 256 + t;
    if (i < N) {
        rowptr[i] += bpre;
        dinv[i] = rsqrtf(1.0f + (float)cnt[i]);   // self-loop => deg >= 1
        if (i == 0) rowptr[N] = E;
    }
}

// ---------------- GEMM1 (BM=32, 6 blocks/CU for cross-block latency hiding) + fill merged ----
// A: 32 rows x 32 k f32 staged via global_load_lds (XOR-swizzled source, linear
// dest), f32->bf16 hi/lo split at fragment-read time. B: pre-swizzled K-tiled
// bf16 hi/lo pack, linear gload_lds. 24KB LDS, grid 1563 -> ~6 blocks/CU.
__global__ __launch_bounds__(256) void k_gemm1fill(
        const float* __restrict__ x,
        const ushort* __restrict__ Bphi, const ushort* __restrict__ Bplo,
        const float* __restrict__ dinv, ushort* __restrict__ h1s,
        int N, int nbG,
        const int* __restrict__ src, const int* __restrict__ dst,
        const int* __restrict__ rank, int E,
        const int* __restrict__ rowptr, int* __restrict__ ssort) {
    __shared__ float  Af[2][1024];                // 2 x 4KB
    __shared__ ushort Bh[2][2048], Bl[2][2048];   // 2 x (4KB + 4KB)

    if (blockIdx.x >= (unsigned)nbG) {
        // ---- fill path ----
        int i = ((blockIdx.x - nbG) * blockDim.x + threadIdx.x) * 2;
        if (i >= E) return;
        if (i + 1 < E) {
            int2 d = *(const int2*)&dst[i];
            int2 s = *(const int2*)&src[i];
            int2 r = *(const int2*)&rank[i];
            ssort[rowptr[d.x] + r.x] = s.x;
            ssort[rowptr[d.y] + r.y] = s.y;
        } else {
            ssort[rowptr[dst[i]] + rank[i]] = src[i];
        }
        return;
    }

    // ---- gemm path ----
    int t = threadIdx.x;
    int wid = t >> 6, lane = t & 63;
    int lr = lane & 15, lko = lane >> 4;
    int wm = wid >> 1, wn = wid & 1;              // wave: 16-row half x 32-col half
    int row0 = blockIdx.x * 32;

    // A staging source: thread t fills LDS physical byte t*16 (one issue/iter)
    int p0 = t * 16;
    int r0l = p0 >> 7;                            // row 0..31
    int o0 = (p0 & 127) ^ ((r0l & 7) << 4);       // swizzled within-row byte
    int g0 = row0 + r0l; if (g0 >= N) g0 = N - 1;
    const char* xsrc0 = (const char*)x + (size_t)g0 * 2048 + o0;
    const char* bsrcH = (const char*)Bphi + (size_t)t * 16;
    const char* bsrcL = (const char*)Bplo + (size_t)t * 16;

    f32x4 acc[2] = {};

    auto stage = [&](int tile, int b) {           // 3 issues/thread
        gl_lds16(xsrc0 + (size_t)tile * 128, (char*)&Af[b][0] + wid * 1024);
        gl_lds16(bsrcH + (size_t)tile * 4096, (char*)&Bh[b][0] + wid * 1024);
        gl_lds16(bsrcL + (size_t)tile * 4096, (char*)&Bl[b][0] + wid * 1024);
    };
    auto compute = [&](int b) {
        int row = wm * 16 + lr;
        int fi = (row * 32 + lko * 8) ^ ((row & 7) << 2);   // float idx, 16B aligned
        f32x4 a0 = *(const f32x4*)&Af[b][fi];
        f32x4 a1 = *(const f32x4*)&Af[b][fi ^ 4];
        float av[8];
        *(f32x4*)&av[0] = a0;
        *(f32x4*)&av[4] = a1;
        bf16x8 ahi, alo;
        #pragma unroll
        for (int j = 0; j < 8; ++j) {
            uint ub = __float_as_uint(av[j]);
            float hf = __uint_as_float(ub & 0xFFFF0000u);
            float lf = av[j] - hf;
            ahi[j] = (short)(ub >> 16);
            alo[j] = (short)(__float_as_uint(lf) >> 16);
        }
        bf16x8 bfh[2], bfl[2];
        #pragma unroll
        for (int nf = 0; nf < 2; ++nf) {
            int col = wn * 32 + nf * 16 + lr;
            int ci = (col * 32 + lko * 8) ^ ((col & 7) << 3);   // ushort idx
            bfh[nf] = *(const bf16x8*)&Bh[b][ci];
            bfl[nf] = *(const bf16x8*)&Bl[b][ci];
        }
        #pragma unroll
        for (int nf = 0; nf < 2; ++nf) {
            acc[nf] = __builtin_amdgcn_mfma_f32_16x16x32_bf16(ahi, bfh[nf], acc[nf], 0, 0, 0);
            acc[nf] = __builtin_amdgcn_mfma_f32_16x16x32_bf16(alo, bfh[nf], acc[nf], 0, 0, 0);
            acc[nf] = __builtin_amdgcn_mfma_f32_16x16x32_bf16(ahi, bfl[nf], acc[nf], 0, 0, 0);
        }
    };

    stage(0, 0);
    __syncthreads();

    #pragma unroll
    for (int i = 0; i < 16; ++i) {
        if (i < 15) stage(i + 1, (i + 1) & 1);    // async prefetch into other buffer
        compute(i & 1);
        __syncthreads();                           // drains vmcnt -> next buffer ready
    }

    // C/D layout (m89-verified): col = lane&15, row = (lane>>4)*4 + reg
    #pragma unroll
    for (int r = 0; r < 4; ++r) {
        int orow = row0 + wm * 16 + lko * 4 + r;
        if (orow < N) {
            float dv = dinv[orow];
            #pragma unroll
            for (int nf = 0; nf < 2; ++nf)
                h1s[(size_t)orow * HID + wn * 32 + nf * 16 + lr] = f2bf(dv * acc[nf][r]);
        }
    }
}

// ---------------- fused agg1 + gemm2 (bf16 h1s gather, bf16 h2s out) ----------------
__global__ __launch_bounds__(256) void k_agg1g2(const ushort* __restrict__ h1s,
                                                const int* __restrict__ rowptr,
                                                const int* __restrict__ ssort,
                                                const float* __restrict__ dinv,
                                                const float* __restrict__ b1,
                                                const float* __restrict__ W2,
                                                ushort* __restrict__ h2s, int N) {
    __shared__ float wl[HID * OUTC];      // 2560 floats = 10.24 KB
    int t = threadIdx.x;
    #pragma unroll
    for (int q0 = 0; q0 < 3; ++q0) {
        int q = t + q0 * 256;
        if (q < 640) *(float4*)&wl[q * 4] = *(const float4*)&W2[q * 4];
    }
    __syncthreads();

    int lane = t & 63;
    int wq = t >> 6;
    int lc = lane < OUTC ? lane : 0;
    float bias = b1[lane];
    int nq = (N + 3) >> 2;

    for (int q = blockIdx.x; q < nq; q += gridDim.x) {
        int node = q * 4 + wq;
        if (node >= N) continue;
        float s0 = bf2f(h1s[(size_t)node * HID + lane]);   // self-loop term
        float sv[GDEPTH];
        #pragma unroll
        for (int k = 0; k < GDEPTH; ++k) sv[k] = 0.f;
        int eu = __builtin_amdgcn_readfirstlane(rowptr[node]);
        int endu = __builtin_amdgcn_readfirstlane(rowptr[node + 1]);
        for (int e = eu; e < endu; e += GDEPTH) {
            int raw[GDEPTH];
            #pragma unroll
            for (int k = 0; k < GDEPTH; ++k) raw[k] = ssort[e + k];  // scalar s_load path
            #pragma unroll
            for (int k = 0; k < GDEPTH; ++k) {
                int ix = (e + k < endu) ? raw[k] : raw[0];
                float v = bf2f(h1s[(size_t)ix * HID + lane]);
                sv[k] += (e + k < endu) ? v : 0.f;
            }
        }
        float s = s0;
        #pragma unroll
        for (int k = 0; k < GDEPTH; ++k) s += sv[k];
        float dv = dinv[node];
        float a = fmaxf(fmaf(dv, s, bias), 0.0f);
        // in-wave gemm2: h2[c] = sum_k a[k] * W2[k][c]
        float acc = 0.f;
        #pragma unroll
        for (int k = 0; k < HID; ++k) {
            float ak = __uint_as_float(__builtin_amdgcn_readlane(__float_as_uint(a), k));
            acc = fmaf(ak, wl[k * OUTC + lc], acc);
        }
        if (lane < OUTC) h2s[(size_t)node * OUTC + lane] = f2bf(dv * acc);
    }
}

// ---------------- agg2 + bias + softmax (bf16 h2s gather) ----------------
__global__ __launch_bounds__(256) void k_agg2(const ushort* __restrict__ h2s,
                                              const int* __restrict__ rowptr,
                                              const int* __restrict__ ssort,
                                              const float* __restrict__ dinv,
                                              const float* __restrict__ b2,
                                              float* __restrict__ out, int N) {
    int lane = threadIdx.x & 63;
    int node = blockIdx.x * 4 + (threadIdx.x >> 6);
    if (node >= N) return;
    bool act = lane < OUTC;
    int lc = act ? lane : 0;
    float s0 = bf2f(h2s[(size_t)node * OUTC + lc]);
    float sv[GDEPTH];
    #pragma unroll
    for (int k = 0; k < GDEPTH; ++k) sv[k] = 0.f;
    int eu = __builtin_amdgcn_readfirstlane(rowptr[node]);
    int endu = __builtin_amdgcn_readfirstlane(rowptr[node + 1]);
    for (int e = eu; e < endu; e += GDEPTH) {
        int raw[GDEPTH];
        #pragma unroll
        for (int k = 0; k < GDEPTH; ++k) raw[k] = ssort[e + k];
        #pragma unroll
        for (int k = 0; k < GDEPTH; ++k) {
            int ix = (e + k < endu) ? raw[k] : raw[0];
            float v = bf2f(h2s[(size_t)ix * OUTC + lc]);
            sv[k] += (e + k < endu) ? v : 0.f;
        }
    }
    float s = s0;
    #pragma unroll
    for (int k = 0; k < GDEPTH; ++k) s += sv[k];
    float v = act ? (dinv[node] * s + b2[lane]) : -INFINITY;
    float m = v;
    #pragma unroll
    for (int o = 32; o; o >>= 1) m = fmaxf(m, __shfl_xor(m, o));
    float p = act ? expf(v - m) : 0.0f;
    float su = p;
    #pragma unroll
    for (int o = 32; o; o >>= 1) su += __shfl_xor(su, o);
    if (act) out[(size_t)node * OUTC + lane] = p / su;
}

static inline size_t alignup(size_t v) { return (v + 255) & ~(size_t)255; }

extern "C" void kernel_launch(void* const* d_in, const int* in_sizes, int n_in,
                              void* d_out, int out_size, void* d_ws, size_t ws_size,
                              hipStream_t stream) {
    const float* x  = (const float*)d_in[0];
    const int*   ei = (const int*)d_in[1];
    const float* W1 = (const float*)d_in[2];
    const float* b1 = (const float*)d_in[3];
    const float* W2 = (const float*)d_in[4];
    const float* b2 = (const float*)d_in[5];

    const int N = in_sizes[0] / IN_C;
    const int E = in_sizes[1] / 2;
    const int* src = ei;
    const int* dst = ei + E;

    char* w = (char*)d_ws;
    int* cnt    = (int*)w;   w += alignup((size_t)N * 4);
    int* rank   = (int*)w;   w += alignup((size_t)E * 4 + 256);
    int* rowptr = (int*)w;   w += alignup((size_t)(N + 1) * 4);
    int* bsum   = (int*)w;   w += alignup(256 * 4);
    int* ssort  = (int*)w;   w += alignup((size_t)E * 4 + 256);  // +pad: scalar tail overreads
    float* dinv = (float*)w; w += alignup((size_t)N * 4);
    ushort* h1s = (ushort*)w; w += alignup((size_t)N * HID * 2);
    ushort* h2s = (ushort*)w; w += alignup((size_t)N * OUTC * 2);
    ushort* Bphi = (ushort*)w; w += alignup((size_t)HID * IN_C * 2);
    ushort* Bplo = (ushort*)w; w += alignup((size_t)HID * IN_C * 2);

    const int n4 = (N + 3) / 4;
    k_zero<<<(n4 + 255) / 256, 256, 0, stream>>>((int4*)cnt, n4);

    const int nb   = (N + 255) / 256;
    const int nbE2 = (E / 2 + 255) / 256;
    const int nbW  = (HID * IN_C + 255) / 256;
    k_histsplit<<<nbE2 + nbW, 256, 0, stream>>>(dst, E, cnt, rank, nbE2, W1, Bphi, Bplo);
    k_scan1 <<<nb, 256, 0, stream>>>(cnt, N, rowptr, bsum);
    k_scan23<<<nb, 256, 0, stream>>>(rowptr, bsum, cnt, dinv, N, E, nb);

    const int nbG = (N + 31) / 32;
    k_gemm1fill<<<nbG + nbE2, 256, 0, stream>>>(x, Bphi, Bplo, dinv, h1s, N, nbG,
                                                src, dst, rank, E, rowptr, ssort);
    k_agg1g2<<<2048, 256, 0, stream>>>(h1s, rowptr, ssort, dinv, b1, W2, h2s, N);
    k_agg2  <<<(N + 3) / 4, 256, 0, stream>>>(h2s, rowptr, ssort, dinv, b2, (float*)d_out, N);
}